// Round 1
// baseline (115.487 us; speedup 1.0000x reference)
//
#include <hip/hip_runtime.h>

// ClustCNNEdgeEncoder: for each edge e=(a,b), gather data[clusts[a]] ++ data[clusts[b]]
// (all 5 cols), overwrite col 3 with (float)e. Output [E*2P, 5] f32, row-major.
// E=40000, P=100 -> per-edge output slab = 200 rows * 5 = 1000 floats (4000 B, 16B-aligned).

#define NPTS_PER_CLUST 100

__global__ __launch_bounds__(256) void ClustCNNEdgeEncoder_88862873354437_kernel(
    const float* __restrict__ data,        // [N_POINTS, 5] f32
    const int*   __restrict__ clusts,      // [N_CLUSTS, 100] int
    const int*   __restrict__ edge_index,  // [2, E] int
    float*       __restrict__ out,         // [E*200*5] f32
    int E)
{
    __shared__ int sh_pts[2 * NPTS_PER_CLUST];  // 200 point indices for this edge

    const int e = blockIdx.x;
    const int t = threadIdx.x;

    // stage the 200 point indices: rows 0..99 from cluster a, 100..199 from cluster b
    if (t < 2 * NPTS_PER_CLUST) {
        const int cl = (t < NPTS_PER_CLUST) ? edge_index[e] : edge_index[E + e];
        const int off = (t < NPTS_PER_CLUST) ? t : t - NPTS_PER_CLUST;
        sh_pts[t] = clusts[cl * NPTS_PER_CLUST + off];
    }
    __syncthreads();

    // 1000 output floats per edge = 250 float4; thread t < 250 writes float4 #t.
    if (t < 250) {
        const float edge_f = (float)e;
        float vals[4];
#pragma unroll
        for (int k = 0; k < 4; ++k) {
            const int el = t * 4 + k;          // flat element in [0,1000)
            const int r  = el / 5;             // row in [0,200)  (magic-mul)
            const int c  = el - r * 5;         // col in [0,5)
            const int p  = sh_pts[r];
            vals[k] = (c == 3) ? edge_f : data[p * 5 + c];
        }
        float4 v;
        v.x = vals[0]; v.y = vals[1]; v.z = vals[2]; v.w = vals[3];
        reinterpret_cast<float4*>(out + (size_t)e * 1000)[t] = v;
    }
}

extern "C" void kernel_launch(void* const* d_in, const int* in_sizes, int n_in,
                              void* d_out, int out_size, void* d_ws, size_t ws_size,
                              hipStream_t stream) {
    const float* data       = (const float*)d_in[0];
    const int*   clusts     = (const int*)d_in[1];
    const int*   edge_index = (const int*)d_in[2];
    float*       out        = (float*)d_out;

    const int E = in_sizes[2] / 2;  // edge_index is [2, E]

    ClustCNNEdgeEncoder_88862873354437_kernel<<<E, 256, 0, stream>>>(
        data, clusts, edge_index, out, E);
}

// Round 3
// 43.162 us; speedup vs baseline: 2.6757x; 2.6757x over previous
//
#include <hip/hip_runtime.h>

// ClustCNNEdgeEncoder: for each edge e=(a,b), gather data[clusts[a]] ++ data[clusts[b]]
// (5 cols), overwrite col 3 with (float)e. Output [E*2P, 5] f32, row-major.
// E=40000, P=100 -> per-edge slab = 1000 floats (4000 B, 16B-aligned).
//
// Two-phase: (1) compact data[clusts[:]] -> d_ws [2000*100*5] f32 (4 MB, L2-resident),
// (2) per-edge float4 copy from compact with col-3 stamp, nontemporal stores.

#define NPTS_PER_CLUST 100

typedef float f32x4 __attribute__((ext_vector_type(4)));  // native vec: OK for nontemporal builtins

// Phase 1: compact[c*500 + j*5 + col] = data[clusts[c*100+j]*5 + col]
__global__ __launch_bounds__(256) void compact_kernel(
    const float* __restrict__ data,     // [N_POINTS, 5]
    const int*   __restrict__ clusts,   // [N_CLUSTS * 100] flat
    float*       __restrict__ compact,  // [N_CLUSTS * 500]
    int total)                          // N_CLUSTS * 500
{
    int tid = blockIdx.x * blockDim.x + threadIdx.x;
    if (tid < total) {
        int row = tid / 5;              // flat index into clusts [0, N_CLUSTS*100)
        int col = tid - row * 5;
        int p   = clusts[row];
        compact[tid] = data[p * 5 + col];
    }
}

// Phase 2: per edge, copy 2 x 125 float4 from compact, stamping col 3 with (float)e.
__global__ __launch_bounds__(256) void edge_copy_kernel(
    const int*   __restrict__ edge_index,  // [2, E]
    const float* __restrict__ compact,     // [N_CLUSTS * 500]
    float*       __restrict__ out,         // [E * 1000]
    int E)
{
    const int e = blockIdx.x;
    const int t = threadIdx.x;
    if (t >= 250) return;

    const int half = (t >= 125);                       // 0: cluster a, 1: cluster b
    const int cl   = edge_index[half * E + e];
    const int ft   = t - half * 125;                   // float4 index within cluster slab

    f32x4 v = reinterpret_cast<const f32x4*>(compact + (size_t)cl * 500)[ft];

    // stamp element where (4t + k) % 5 == 3
    const int m = (t * 4) % 5;
    const int k = (3 - m + 5) % 5;                     // k in [0,4]; k==4 -> no stamp
    const float ef = (float)e;
    if (k < 4) v[k] = ef;

    __builtin_nontemporal_store(v, reinterpret_cast<f32x4*>(out + (size_t)e * 1000) + t);
}

// Fallback (ws too small): direct gather, same as R1 kernel.
__global__ __launch_bounds__(256) void direct_kernel(
    const float* __restrict__ data,
    const int*   __restrict__ clusts,
    const int*   __restrict__ edge_index,
    float*       __restrict__ out,
    int E)
{
    __shared__ int sh_pts[2 * NPTS_PER_CLUST];
    const int e = blockIdx.x;
    const int t = threadIdx.x;
    if (t < 2 * NPTS_PER_CLUST) {
        const int cl  = (t < NPTS_PER_CLUST) ? edge_index[e] : edge_index[E + e];
        const int off = (t < NPTS_PER_CLUST) ? t : t - NPTS_PER_CLUST;
        sh_pts[t] = clusts[cl * NPTS_PER_CLUST + off];
    }
    __syncthreads();
    if (t < 250) {
        const float edge_f = (float)e;
        float vals[4];
#pragma unroll
        for (int kk = 0; kk < 4; ++kk) {
            const int el = t * 4 + kk;
            const int r  = el / 5;
            const int c  = el - r * 5;
            vals[kk] = (c == 3) ? edge_f : data[sh_pts[r] * 5 + c];
        }
        float4 v; v.x = vals[0]; v.y = vals[1]; v.z = vals[2]; v.w = vals[3];
        reinterpret_cast<float4*>(out + (size_t)e * 1000)[t] = v;
    }
}

extern "C" void kernel_launch(void* const* d_in, const int* in_sizes, int n_in,
                              void* d_out, int out_size, void* d_ws, size_t ws_size,
                              hipStream_t stream) {
    const float* data       = (const float*)d_in[0];
    const int*   clusts     = (const int*)d_in[1];
    const int*   edge_index = (const int*)d_in[2];
    float*       out        = (float*)d_out;

    const int E        = in_sizes[2] / 2;          // edge_index is [2, E]
    const int n_clpts  = in_sizes[1];              // N_CLUSTS * 100
    const int total    = n_clpts * 5;              // compact element count
    const size_t need  = (size_t)total * sizeof(float);

    if (ws_size >= need) {
        float* compact = (float*)d_ws;
        compact_kernel<<<(total + 255) / 256, 256, 0, stream>>>(data, clusts, compact, total);
        edge_copy_kernel<<<E, 256, 0, stream>>>(edge_index, compact, out, E);
    } else {
        direct_kernel<<<E, 256, 0, stream>>>(data, clusts, edge_index, out, E);
    }
}